// Round 1
// baseline (825.953 us; speedup 1.0000x reference)
//
#include <hip/hip_runtime.h>
#include <cmath>

#define BATCH 1024

// ---------------- Level 0: diva0, r0, base us0, + f/a passthrough ----------------
__global__ __launch_bounds__(256) void k_level0(
    const float* __restrict__ u, const float* __restrict__ f, const float* __restrict__ a,
    const float* __restrict__ c0w, const float* __restrict__ c0b,
    const float* __restrict__ c1w, const float* __restrict__ c1b,
    float* __restrict__ out_us0, float* __restrict__ out_diva0, float* __restrict__ ws_r0,
    float* __restrict__ out_f, float* __restrict__ out_a)
{
    const int b = blockIdx.z;
    const int y0 = blockIdx.y * 16, x0 = blockIdx.x * 16;
    const int tx = threadIdx.x & 15, ty = threadIdx.x >> 4;
    __shared__ float a_s[19][20];   // a tile, origin (y0-1, x0-1)
    __shared__ float td[18][19];    // tanh(diva), origin (y0-1, x0-1)

    const float* ab = a + (size_t)b * 16384;
    for (int idx = threadIdx.x; idx < 19 * 19; idx += 256) {
        int r = idx / 19, c = idx % 19;
        int gy = y0 - 1 + r; gy = gy < 0 ? 0 : (gy > 127 ? 127 : gy);
        int gx = x0 - 1 + c; gx = gx < 0 ? 0 : (gx > 127 ? 127 : gx);
        a_s[r][c] = ab[gy * 128 + gx];
    }
    __syncthreads();
    const float w00 = c1w[0], w01 = c1w[1], w10 = c1w[2], w11 = c1w[3];
    const float b1 = c1b[0];
    for (int idx = threadIdx.x; idx < 18 * 18; idx += 256) {
        int r = idx / 18, c = idx % 18;
        int dy = y0 - 1 + r, dx = x0 - 1 + c;
        if (dy >= 0 && dy <= 126 && dx >= 0 && dx <= 126) {
            float d = a_s[r][c] * w00 + a_s[r][c + 1] * w01
                    + a_s[r + 1][c] * w10 + a_s[r + 1][c + 1] * w11 + b1;
            td[r][c] = tanhf(d);
        }
    }
    __syncthreads();
    const int y = y0 + ty, x = x0 + tx;
    // a passthrough (covers full 128x128)
    out_a[(size_t)b * 16384 + (size_t)y * 128 + x] = a_s[ty + 1][tx + 1];
    if (y < 127 && x < 127) {
        float diva = a_s[ty + 1][tx + 1] * w00 + a_s[ty + 1][tx + 2] * w01
                   + a_s[ty + 2][tx + 1] * w10 + a_s[ty + 2][tx + 2] * w11 + b1;
        size_t idx = (size_t)b * 16129 + (size_t)y * 127 + x;
        float uv = u[idx], fv = f[idx];
        float rv = fv - diva * uv;
        float s = c0b[0];
        #pragma unroll
        for (int ky = 0; ky < 3; ky++) {
            int sy = y - 1 + ky; sy = sy < 0 ? 0 : (sy > 126 ? 126 : sy);
            int lr = sy - (y0 - 1);
            #pragma unroll
            for (int kx = 0; kx < 3; kx++) {
                int sx = x - 1 + kx; sx = sx < 0 ? 0 : (sx > 126 ? 126 : sx);
                s += c0w[ky * 3 + kx] * td[lr][sx - (x0 - 1)];
            }
        }
        out_diva0[idx] = diva;
        ws_r0[idx] = rv;
        out_us0[idx] = uv + s * rv;
        out_f[idx] = fv;   // f passthrough
    }
}

// ---------------- Level 1 restrict + Conv_Dyn (LDS-staged coalesced reads) ----------------
__global__ __launch_bounds__(256) void k_restrict1(
    const float* __restrict__ a_prev, const float* __restrict__ r_prev,
    float* __restrict__ a_out, float* __restrict__ r_out,
    float* __restrict__ us_out, float* __restrict__ diva_out,
    const float* __restrict__ r1w, const float* __restrict__ r3w,
    const float* __restrict__ c1w, const float* __restrict__ c1b,
    const float* __restrict__ c0w, const float* __restrict__ c0b)
{
    const int n = 63, na = 64, npa = 128, npd = 127;
    const int b = blockIdx.z;
    const int y0 = blockIdx.y * 16, x0 = blockIdx.x * 16;
    const int tx = threadIdx.x & 15, ty = threadIdx.x >> 4;
    __shared__ float asrc[38][40];   // raw a region [2y0-2 .. 2y0+35]^2 (clamped)
    __shared__ float rsrc[33][34];   // raw r region [2y0 .. 2y0+32]^2 (clamped)
    __shared__ float a_s[19][20];    // restricted a tile, origin (y0-1, x0-1)
    __shared__ float td[18][19];

    const float* apb = a_prev + (size_t)b * npa * npa;
    const float* rpb = r_prev + (size_t)b * npd * npd;

    for (int idx = threadIdx.x; idx < 38 * 38; idx += 256) {
        int rr = idx / 38, cc = idx % 38;
        int gy = 2 * y0 - 2 + rr; gy = gy < 0 ? 0 : (gy > npa - 1 ? npa - 1 : gy);
        int gx = 2 * x0 - 2 + cc; gx = gx < 0 ? 0 : (gx > npa - 1 ? npa - 1 : gx);
        asrc[rr][cc] = apb[(size_t)gy * npa + gx];
    }
    for (int idx = threadIdx.x; idx < 33 * 33; idx += 256) {
        int rr = idx / 33, cc = idx % 33;
        int gy = 2 * y0 + rr; if (gy > npd - 1) gy = npd - 1;
        int gx = 2 * x0 + cc; if (gx > npd - 1) gx = npd - 1;
        rsrc[rr][cc] = rpb[(size_t)gy * npd + gx];
    }
    __syncthreads();

    const float q00 = r1w[0], q01 = r1w[1], q10 = r1w[2], q11 = r1w[3];
    for (int idx = threadIdx.x; idx < 19 * 19; idx += 256) {
        int r = idx / 19, c = idx % 19;
        int ay = y0 - 1 + r; ay = ay < 0 ? 0 : (ay > na - 1 ? na - 1 : ay);
        int ax = x0 - 1 + c; ax = ax < 0 ? 0 : (ax > na - 1 ? na - 1 : ax);
        int lr = 2 * (ay - y0 + 1), lc = 2 * (ax - x0 + 1);
        a_s[r][c] = asrc[lr][lc] * q00 + asrc[lr][lc + 1] * q01
                  + asrc[lr + 1][lc] * q10 + asrc[lr + 1][lc + 1] * q11;
    }
    __syncthreads();
    const float w00 = c1w[0], w01 = c1w[1], w10 = c1w[2], w11 = c1w[3], b1 = c1b[0];
    for (int idx = threadIdx.x; idx < 18 * 18; idx += 256) {
        int r = idx / 18, c = idx % 18;
        int dy = y0 - 1 + r, dx = x0 - 1 + c;
        if (dy >= 0 && dy < n && dx >= 0 && dx < n) {
            float d = a_s[r][c] * w00 + a_s[r][c + 1] * w01
                    + a_s[r + 1][c] * w10 + a_s[r + 1][c + 1] * w11 + b1;
            td[r][c] = tanhf(d);
        }
    }
    __syncthreads();
    const int y = y0 + ty, x = x0 + tx;
    if (y < na && x < na)
        a_out[(size_t)b * na * na + (size_t)y * na + x] = a_s[ty + 1][tx + 1];
    if (y < n && x < n) {
        float diva = a_s[ty + 1][tx + 1] * w00 + a_s[ty + 1][tx + 2] * w01
                   + a_s[ty + 2][tx + 1] * w10 + a_s[ty + 2][tx + 2] * w11 + b1;
        float rv = 0.f;
        #pragma unroll
        for (int p = 0; p < 3; p++)
            #pragma unroll
            for (int q = 0; q < 3; q++)
                rv += r3w[p * 3 + q] * rsrc[2 * (y - y0) + p][2 * (x - x0) + q];
        float s = c0b[0];
        #pragma unroll
        for (int ky = 0; ky < 3; ky++) {
            int sy = y - 1 + ky; sy = sy < 0 ? 0 : (sy > n - 1 ? n - 1 : sy);
            int lr = sy - (y0 - 1);
            #pragma unroll
            for (int kx = 0; kx < 3; kx++) {
                int sx = x - 1 + kx; sx = sx < 0 ? 0 : (sx > n - 1 ? n - 1 : sx);
                s += c0w[ky * 3 + kx] * td[lr][sx - (x0 - 1)];
            }
        }
        size_t idx = (size_t)b * n * n + (size_t)y * n + x;
        diva_out[idx] = diva;
        r_out[idx] = rv;
        us_out[idx] = s * rv;
    }
}

// ---------------- Fused levels 2..4 + prolong 4->3->2 (one block per image) ----------------
template<int N, int NA, int PA, int PD>
__device__ __forceinline__ void level_step(
    const float* ap, const float* rp, float* ac, float* rc, float* us, float* td,
    const float* __restrict__ r1w, const float* __restrict__ r3w,
    const float* __restrict__ c1w, float c1b_,
    const float* __restrict__ c0w, float c0b_,
    float* __restrict__ diva_out, int tid)
{
    const float q00 = r1w[0], q01 = r1w[1], q10 = r1w[2], q11 = r1w[3];
    for (int idx = tid; idx < NA * NA; idx += 256) {
        int y = idx / NA, x = idx % NA;
        const float* p = ap + 2 * y * PA + 2 * x;
        ac[idx] = p[0] * q00 + p[1] * q01 + p[PA] * q10 + p[PA + 1] * q11;
    }
    __syncthreads();
    const float w00 = c1w[0], w01 = c1w[1], w10 = c1w[2], w11 = c1w[3];
    for (int idx = tid; idx < N * N; idx += 256) {
        int y = idx / N, x = idx % N;
        float d = ac[y * NA + x] * w00 + ac[y * NA + x + 1] * w01
                + ac[(y + 1) * NA + x] * w10 + ac[(y + 1) * NA + x + 1] * w11 + c1b_;
        td[idx] = tanhf(d);
        diva_out[idx] = d;
    }
    __syncthreads();
    for (int idx = tid; idx < N * N; idx += 256) {
        int y = idx / N, x = idx % N;
        float rv = 0.f;
        #pragma unroll
        for (int p = 0; p < 3; p++)
            #pragma unroll
            for (int q = 0; q < 3; q++)
                rv += r3w[p * 3 + q] * rp[(2 * y + p) * PD + 2 * x + q];
        float s = c0b_;
        #pragma unroll
        for (int ky = 0; ky < 3; ky++) {
            int sy = y - 1 + ky; sy = sy < 0 ? 0 : (sy > N - 1 ? N - 1 : sy);
            #pragma unroll
            for (int kx = 0; kx < 3; kx++) {
                int sx = x - 1 + kx; sx = sx < 0 ? 0 : (sx > N - 1 ? N - 1 : sx);
                s += c0w[ky * 3 + kx] * td[sy * N + sx];
            }
        }
        rc[idx] = rv;
        us[idx] = s * rv;
    }
    __syncthreads();
}

template<int NO, int NI>
__device__ __forceinline__ void prolong_step(
    float* uo, const float* ui, const float* __restrict__ tw9, int tid)
{
    for (int idx = tid; idx < NO * NO; idx += 256) {
        int y = idx / NO, x = idx % NO;
        float acc = 0.f;
        #pragma unroll
        for (int ky = 0; ky < 3; ky++) {
            int sy = y - ky;
            if (sy & 1) continue;
            int iy = sy >> 1;
            if (iy < 0 || iy >= NI) continue;
            #pragma unroll
            for (int kx = 0; kx < 3; kx++) {
                int sx = x - kx;
                if (sx & 1) continue;
                int ix = sx >> 1;
                if (ix < 0 || ix >= NI) continue;
                acc += tw9[ky * 3 + kx] * ui[iy * NI + ix];
            }
        }
        uo[idx] += acc;
    }
    __syncthreads();
}

__global__ __launch_bounds__(256) void k_coarse(
    const float* __restrict__ a1, const float* __restrict__ r1,
    const float* __restrict__ r1w, const float* __restrict__ r3w,
    const float* __restrict__ c1w, const float* __restrict__ c1b,
    const float* __restrict__ c0w, const float* __restrict__ c0b,
    const float* __restrict__ tw,
    float* __restrict__ diva2, float* __restrict__ diva3, float* __restrict__ diva4,
    float* __restrict__ us2_out)
{
    const int b = blockIdx.x;
    const int tid = threadIdx.x;
    __shared__ float aA[64 * 64];
    __shared__ float rA[63 * 63];
    __shared__ float aB[32 * 32];
    __shared__ float rB[31 * 31];
    __shared__ float aC[16 * 16];
    __shared__ float rC[15 * 15];
    __shared__ float aD[8 * 8];
    __shared__ float rD[7 * 7];
    __shared__ float us2s[31 * 31];
    __shared__ float us3s[15 * 15];
    __shared__ float us4s[7 * 7];
    __shared__ float td[31 * 31];

    const float* a1b = a1 + (size_t)b * 4096;
    const float* r1b = r1 + (size_t)b * 3969;
    for (int i = tid; i < 4096; i += 256) aA[i] = a1b[i];
    for (int i = tid; i < 3969; i += 256) rA[i] = r1b[i];
    __syncthreads();

    level_step<31, 32, 64, 63>(aA, rA, aB, rB, us2s, td,
        r1w + 4, r3w + 9, c1w + 8, c1b[2], c0w + 18, c0b[2],
        diva2 + (size_t)b * 961, tid);
    level_step<15, 16, 32, 31>(aB, rB, aC, rC, us3s, td,
        r1w + 8, r3w + 18, c1w + 12, c1b[3], c0w + 27, c0b[3],
        diva3 + (size_t)b * 225, tid);
    level_step<7, 8, 16, 15>(aC, rC, aD, rD, us4s, td,
        r1w + 12, r3w + 27, c1w + 16, c1b[4], c0w + 36, c0b[4],
        diva4 + (size_t)b * 49, tid);

    prolong_step<15, 7>(us3s, us4s, tw + 27, tid);
    prolong_step<31, 15>(us2s, us3s, tw + 18, tid);

    for (int i = tid; i < 961; i += 256)
        us2_out[(size_t)b * 961 + i] = us2s[i];
}

// ---------------- Prolongation: us_out += convT3 s2 (us_in) ----------------
__global__ __launch_bounds__(256) void k_prolong(
    float* __restrict__ us_out, const float* __restrict__ us_in,
    const float* __restrict__ tw, int n_out, int n_in)
{
    const int b = blockIdx.z;
    const int y = blockIdx.y * 16 + (threadIdx.x >> 4);
    const int x = blockIdx.x * 16 + (threadIdx.x & 15);
    if (y >= n_out || x >= n_out) return;
    const float* ib = us_in + (size_t)b * n_in * n_in;
    float acc = 0.f;
    #pragma unroll
    for (int ky = 0; ky < 3; ky++) {
        int sy = y - ky;
        if (sy & 1) continue;
        int iy = sy >> 1;
        if (iy < 0 || iy >= n_in) continue;
        #pragma unroll
        for (int kx = 0; kx < 3; kx++) {
            int sx = x - kx;
            if (sx & 1) continue;
            int ix = sx >> 1;
            if (ix < 0 || ix >= n_in) continue;
            acc += tw[ky * 3 + kx] * ib[(size_t)iy * n_in + ix];
        }
    }
    size_t idx = (size_t)b * n_out * n_out + (size_t)y * n_out + x;
    us_out[idx] += acc;
}

extern "C" void kernel_launch(void* const* d_in, const int* in_sizes, int n_in,
                              void* d_out, int out_size, void* d_ws, size_t ws_size,
                              hipStream_t stream) {
    const float* u   = (const float*)d_in[0];
    const float* f   = (const float*)d_in[1];
    const float* a   = (const float*)d_in[2];
    const float* c0w = (const float*)d_in[3];
    const float* c0b = (const float*)d_in[4];
    const float* c1w = (const float*)d_in[5];
    const float* c1b = (const float*)d_in[6];
    const float* r1w = (const float*)d_in[7];
    const float* r3w = (const float*)d_in[8];
    const float* tw  = (const float*)d_in[9];
    float* out = (float*)d_out;
    float* ws  = (float*)d_ws;
    const size_t B = BATCH;

    // d_out layout: us0, f, a, diva0..diva4
    size_t off_us0 = 0;
    size_t off_f   = B * 16129;
    size_t off_a   = off_f + B * 16129;
    size_t off_d0  = off_a + B * 16384;
    size_t off_d1  = off_d0 + B * 16129;
    size_t off_d2  = off_d1 + B * 3969;
    size_t off_d3  = off_d2 + B * 961;
    size_t off_d4  = off_d3 + B * 225;

    // ws layout: r0, a1, r1, us1, us2
    size_t w_r0  = 0;
    size_t w_a1  = w_r0 + B * 16129;
    size_t w_r1  = w_a1 + B * 4096;
    size_t w_us1 = w_r1 + B * 3969;
    size_t w_us2 = w_us1 + B * 3969;

    dim3 blk(256);
    k_level0<<<dim3(8, 8, B), blk, 0, stream>>>(
        u, f, a, c0w, c0b, c1w, c1b,
        out + off_us0, out + off_d0, ws + w_r0, out + off_f, out + off_a);

    k_restrict1<<<dim3(4, 4, B), blk, 0, stream>>>(
        a, ws + w_r0, ws + w_a1, ws + w_r1, ws + w_us1, out + off_d1,
        r1w, r3w, c1w + 4, c1b + 1, c0w + 9, c0b + 1);

    k_coarse<<<dim3(1024), blk, 0, stream>>>(
        ws + w_a1, ws + w_r1, r1w, r3w, c1w, c1b, c0w, c0b, tw,
        out + off_d2, out + off_d3, out + off_d4, ws + w_us2);

    k_prolong<<<dim3(4, 4, B), blk, 0, stream>>>(
        ws + w_us1, ws + w_us2, tw + 9, 63, 31);

    k_prolong<<<dim3(8, 8, B), blk, 0, stream>>>(
        out + off_us0, ws + w_us1, tw + 0, 127, 63);
}

// Round 2
// 641.314 us; speedup vs baseline: 1.2879x; 1.2879x over previous
//
#include <hip/hip_runtime.h>
#include <cmath>

#define BATCH 1024
#define R0 16
#define R1 8
#define RP 8

// ---------------- Level 0: row-stripe. diva0, r0, us0, + f/a passthrough ----------------
__global__ __launch_bounds__(256) void k_level0(
    const float* __restrict__ u, const float* __restrict__ f, const float* __restrict__ a,
    const float* __restrict__ c0w, const float* __restrict__ c0b,
    const float* __restrict__ c1w, const float* __restrict__ c1b,
    float* __restrict__ out_us0, float* __restrict__ out_diva0, float* __restrict__ ws_r0,
    float* __restrict__ out_f, float* __restrict__ out_a)
{
    const int b = blockIdx.y;
    const int y0 = blockIdx.x * R0;          // 0,16,...,112
    const int tid = threadIdx.x;
    __shared__ float a_s[R0 + 3][128];       // a rows y0-1 .. y0+R0+1 (clamped)
    __shared__ float td[R0 + 2][128];        // tanh(diva) rows y0-1 .. y0+R0 (where valid)

    const float* ab = a + (size_t)b * 16384;
    for (int i = tid; i < (R0 + 3) * 128; i += 256) {
        int r = i >> 7, c = i & 127;
        int gy = y0 - 1 + r; gy = gy < 0 ? 0 : (gy > 127 ? 127 : gy);
        a_s[r][c] = ab[gy * 128 + c];
    }
    __syncthreads();
    const float w00 = c1w[0], w01 = c1w[1], w10 = c1w[2], w11 = c1w[3];
    const float b1 = c1b[0];
    for (int i = tid; i < (R0 + 2) * 127; i += 256) {
        int r = i / 127, c = i % 127;
        int dr = y0 - 1 + r;
        if (dr >= 0 && dr <= 126) {
            float d = a_s[r][c] * w00 + a_s[r][c + 1] * w01
                    + a_s[r + 1][c] * w10 + a_s[r + 1][c + 1] * w11 + b1;
            td[r][c] = tanhf(d);
        }
    }
    __syncthreads();
    // a passthrough: rows y0..y0+15, all 128 cols (contiguous 8KB block)
    float* oa = out_a + (size_t)b * 16384 + (size_t)y0 * 128;
    for (int i = tid; i < R0 * 128; i += 256)
        oa[i] = a_s[(i >> 7) + 1][i & 127];
    // main outputs: rows y0..y0+15 (y<127), cols 0..126 — contiguous row writes
    for (int i = tid; i < R0 * 127; i += 256) {
        int row = i / 127, col = i % 127;
        int y = y0 + row;
        if (y >= 127) continue;
        float diva = a_s[row + 1][col] * w00 + a_s[row + 1][col + 1] * w01
                   + a_s[row + 2][col] * w10 + a_s[row + 2][col + 1] * w11 + b1;
        size_t idx = (size_t)b * 16129 + (size_t)y * 127 + col;
        float uv = u[idx], fv = f[idx];
        float rv = fv - diva * uv;
        float s = c0b[0];
        #pragma unroll
        for (int ky = 0; ky < 3; ky++) {
            int sy = y - 1 + ky; sy = sy < 0 ? 0 : (sy > 126 ? 126 : sy);
            int lr = sy - (y0 - 1);
            #pragma unroll
            for (int kx = 0; kx < 3; kx++) {
                int sx = col - 1 + kx; sx = sx < 0 ? 0 : (sx > 126 ? 126 : sx);
                s += c0w[ky * 3 + kx] * td[lr][sx];
            }
        }
        out_diva0[idx] = diva;
        ws_r0[idx] = rv;
        out_us0[idx] = uv + s * rv;
        out_f[idx] = fv;
    }
}

// ---------------- Level 1: row-stripe restrict + Conv_Dyn ----------------
__global__ __launch_bounds__(256) void k_restrict1(
    const float* __restrict__ a_prev, const float* __restrict__ r_prev,
    float* __restrict__ a_out, float* __restrict__ r_out,
    float* __restrict__ us_out, float* __restrict__ diva_out,
    const float* __restrict__ r1w, const float* __restrict__ r3w,
    const float* __restrict__ c1w, const float* __restrict__ c1b,
    const float* __restrict__ c0w, const float* __restrict__ c0b)
{
    const int b = blockIdx.y;
    const int y0 = blockIdx.x * R1;          // 0,8,...,56 (a1 rows y0..y0+7)
    const int tid = threadIdx.x;
    __shared__ float asrc[2 * R1 + 6][128];  // a rows 2y0-2 .. 2y0+19 (clamped): 22 rows
    __shared__ float rsrc[2 * R1 + 1][128];  // r0 rows 2y0 .. 2y0+16 (clamped): 17 rows x 127
    __shared__ float a_s[R1 + 3][66];        // a1 rows y0-1..y0+9 (clamped), cols -1..64 (clamped)
    __shared__ float td[R1 + 2][64];         // tanh(diva1) rows y0-1..y0+8, cols 0..62

    const float* apb = a_prev + (size_t)b * 16384;
    for (int i = tid; i < (2 * R1 + 6) * 128; i += 256) {
        int r = i >> 7, c = i & 127;
        int gy = 2 * y0 - 2 + r; gy = gy < 0 ? 0 : (gy > 127 ? 127 : gy);
        asrc[r][c] = apb[gy * 128 + c];
    }
    const float* rpb = r_prev + (size_t)b * 16129;
    for (int i = tid; i < (2 * R1 + 1) * 127; i += 256) {
        int r = i / 127, c = i % 127;
        int gy = 2 * y0 + r; if (gy > 126) gy = 126;
        rsrc[r][c] = rpb[gy * 127 + c];
    }
    __syncthreads();
    const float q00 = r1w[0], q01 = r1w[1], q10 = r1w[2], q11 = r1w[3];
    for (int i = tid; i < (R1 + 3) * 66; i += 256) {
        int r = i / 66, c = i % 66;
        int ay = y0 - 1 + r; ay = ay < 0 ? 0 : (ay > 63 ? 63 : ay);
        int ax = c - 1; ax = ax < 0 ? 0 : (ax > 63 ? 63 : ax);
        int la = 2 * ay - (2 * y0 - 2);
        a_s[r][c] = asrc[la][2 * ax] * q00 + asrc[la][2 * ax + 1] * q01
                  + asrc[la + 1][2 * ax] * q10 + asrc[la + 1][2 * ax + 1] * q11;
    }
    __syncthreads();
    const float w00 = c1w[0], w01 = c1w[1], w10 = c1w[2], w11 = c1w[3], b1 = c1b[0];
    for (int i = tid; i < (R1 + 2) * 63; i += 256) {
        int r = i / 63, c = i % 63;
        int dr = y0 - 1 + r;
        if (dr >= 0 && dr <= 62) {
            float d = a_s[r][c + 1] * w00 + a_s[r][c + 2] * w01
                    + a_s[r + 1][c + 1] * w10 + a_s[r + 1][c + 2] * w11 + b1;
            td[r][c] = tanhf(d);
        }
    }
    __syncthreads();
    // a1 out: rows y0..y0+7 x 64 cols — contiguous 2KB block
    float* a1o = a_out + (size_t)b * 4096 + (size_t)y0 * 64;
    for (int i = tid; i < R1 * 64; i += 256)
        a1o[i] = a_s[(i >> 6) + 1][(i & 63) + 1];
    // us1/r1/diva1: rows y0..min(y0+7,62), cols 0..62 — contiguous row writes
    for (int i = tid; i < R1 * 63; i += 256) {
        int row = i / 63, col = i % 63;
        int y = y0 + row;
        if (y >= 63) continue;
        float diva = a_s[row + 1][col + 1] * w00 + a_s[row + 1][col + 2] * w01
                   + a_s[row + 2][col + 1] * w10 + a_s[row + 2][col + 2] * w11 + b1;
        float rv = 0.f;
        #pragma unroll
        for (int p = 0; p < 3; p++)
            #pragma unroll
            for (int q = 0; q < 3; q++)
                rv += r3w[p * 3 + q] * rsrc[2 * row + p][2 * col + q];
        float s = c0b[0];
        #pragma unroll
        for (int ky = 0; ky < 3; ky++) {
            int sy = y - 1 + ky; sy = sy < 0 ? 0 : (sy > 62 ? 62 : sy);
            int lr = sy - (y0 - 1);
            #pragma unroll
            for (int kx = 0; kx < 3; kx++) {
                int sx = col - 1 + kx; sx = sx < 0 ? 0 : (sx > 62 ? 62 : sx);
                s += c0w[ky * 3 + kx] * td[lr][sx];
            }
        }
        size_t idx = (size_t)b * 3969 + (size_t)y * 63 + col;
        diva_out[idx] = diva;
        r_out[idx] = rv;
        us_out[idx] = s * rv;
    }
}

// ---------------- Fused levels 2..4 + prolong 4->3->2 (one block per image) ----------------
template<int N, int NA, int PA, int PD>
__device__ __forceinline__ void level_step(
    const float* ap, const float* rp, float* ac, float* rc, float* us, float* td,
    const float* __restrict__ r1w, const float* __restrict__ r3w,
    const float* __restrict__ c1w, float c1b_,
    const float* __restrict__ c0w, float c0b_,
    float* __restrict__ diva_out, int tid)
{
    const float q00 = r1w[0], q01 = r1w[1], q10 = r1w[2], q11 = r1w[3];
    for (int idx = tid; idx < NA * NA; idx += 256) {
        int y = idx / NA, x = idx % NA;
        const float* p = ap + 2 * y * PA + 2 * x;
        ac[idx] = p[0] * q00 + p[1] * q01 + p[PA] * q10 + p[PA + 1] * q11;
    }
    __syncthreads();
    const float w00 = c1w[0], w01 = c1w[1], w10 = c1w[2], w11 = c1w[3];
    for (int idx = tid; idx < N * N; idx += 256) {
        int y = idx / N, x = idx % N;
        float d = ac[y * NA + x] * w00 + ac[y * NA + x + 1] * w01
                + ac[(y + 1) * NA + x] * w10 + ac[(y + 1) * NA + x + 1] * w11 + c1b_;
        td[idx] = tanhf(d);
        diva_out[idx] = d;
    }
    __syncthreads();
    for (int idx = tid; idx < N * N; idx += 256) {
        int y = idx / N, x = idx % N;
        float rv = 0.f;
        #pragma unroll
        for (int p = 0; p < 3; p++)
            #pragma unroll
            for (int q = 0; q < 3; q++)
                rv += r3w[p * 3 + q] * rp[(2 * y + p) * PD + 2 * x + q];
        float s = c0b_;
        #pragma unroll
        for (int ky = 0; ky < 3; ky++) {
            int sy = y - 1 + ky; sy = sy < 0 ? 0 : (sy > N - 1 ? N - 1 : sy);
            #pragma unroll
            for (int kx = 0; kx < 3; kx++) {
                int sx = x - 1 + kx; sx = sx < 0 ? 0 : (sx > N - 1 ? N - 1 : sx);
                s += c0w[ky * 3 + kx] * td[sy * N + sx];
            }
        }
        rc[idx] = rv;
        us[idx] = s * rv;
    }
    __syncthreads();
}

template<int NO, int NI>
__device__ __forceinline__ void prolong_step(
    float* uo, const float* ui, const float* __restrict__ tw9, int tid)
{
    for (int idx = tid; idx < NO * NO; idx += 256) {
        int y = idx / NO, x = idx % NO;
        float acc = 0.f;
        #pragma unroll
        for (int ky = 0; ky < 3; ky++) {
            int sy = y - ky;
            if (sy & 1) continue;
            int iy = sy >> 1;
            if (iy < 0 || iy >= NI) continue;
            #pragma unroll
            for (int kx = 0; kx < 3; kx++) {
                int sx = x - kx;
                if (sx & 1) continue;
                int ix = sx >> 1;
                if (ix < 0 || ix >= NI) continue;
                acc += tw9[ky * 3 + kx] * ui[iy * NI + ix];
            }
        }
        uo[idx] += acc;
    }
    __syncthreads();
}

__global__ __launch_bounds__(256) void k_coarse(
    const float* __restrict__ a1, const float* __restrict__ r1,
    const float* __restrict__ r1w, const float* __restrict__ r3w,
    const float* __restrict__ c1w, const float* __restrict__ c1b,
    const float* __restrict__ c0w, const float* __restrict__ c0b,
    const float* __restrict__ tw,
    float* __restrict__ diva2, float* __restrict__ diva3, float* __restrict__ diva4,
    float* __restrict__ us2_out)
{
    const int b = blockIdx.x;
    const int tid = threadIdx.x;
    __shared__ float aA[64 * 64];
    __shared__ float rA[63 * 63];
    __shared__ float aB[32 * 32];
    __shared__ float rB[31 * 31];
    __shared__ float aC[16 * 16];
    __shared__ float rC[15 * 15];
    __shared__ float aD[8 * 8];
    __shared__ float rD[7 * 7];
    __shared__ float us2s[31 * 31];
    __shared__ float us3s[15 * 15];
    __shared__ float us4s[7 * 7];
    __shared__ float td[31 * 31];

    const float* a1b = a1 + (size_t)b * 4096;
    const float* r1b = r1 + (size_t)b * 3969;
    for (int i = tid; i < 4096; i += 256) aA[i] = a1b[i];
    for (int i = tid; i < 3969; i += 256) rA[i] = r1b[i];
    __syncthreads();

    level_step<31, 32, 64, 63>(aA, rA, aB, rB, us2s, td,
        r1w + 4, r3w + 9, c1w + 8, c1b[2], c0w + 18, c0b[2],
        diva2 + (size_t)b * 961, tid);
    level_step<15, 16, 32, 31>(aB, rB, aC, rC, us3s, td,
        r1w + 8, r3w + 18, c1w + 12, c1b[3], c0w + 27, c0b[3],
        diva3 + (size_t)b * 225, tid);
    level_step<7, 8, 16, 15>(aC, rC, aD, rD, us4s, td,
        r1w + 12, r3w + 27, c1w + 16, c1b[4], c0w + 36, c0b[4],
        diva4 + (size_t)b * 49, tid);

    prolong_step<15, 7>(us3s, us4s, tw + 27, tid);
    prolong_step<31, 15>(us2s, us3s, tw + 18, tid);

    for (int i = tid; i < 961; i += 256)
        us2_out[(size_t)b * 961 + i] = us2s[i];
}

// ---------------- Prolongation: row-stripe. us_out += convT3 s2 (us_in) ----------------
__global__ __launch_bounds__(256) void k_prolong(
    float* __restrict__ us_out, const float* __restrict__ us_in,
    const float* __restrict__ tw, int n_out, int n_in)
{
    const int b = blockIdx.y;
    const int y0 = blockIdx.x * RP;
    const int tid = threadIdx.x;
    __shared__ float in_s[RP / 2 + 2][128];
    const int iy_base = (y0 >> 1) - 1;
    const float* ib = us_in + (size_t)b * n_in * n_in;
    for (int i = tid; i < (RP / 2 + 2) * n_in; i += 256) {
        int r = i / n_in, c = i % n_in;
        int iy = iy_base + r;
        if (iy >= 0 && iy < n_in) in_s[r][c] = ib[iy * n_in + c];
    }
    __syncthreads();
    for (int i = tid; i < RP * n_out; i += 256) {
        int row = i / n_out, col = i % n_out;
        int y = y0 + row;
        if (y >= n_out) continue;
        float acc = 0.f;
        #pragma unroll
        for (int ky = 0; ky < 3; ky++) {
            int sy = y - ky;
            if ((sy & 1) || sy < 0) continue;
            int iy = sy >> 1;
            if (iy >= n_in) continue;
            int lr = iy - iy_base;
            #pragma unroll
            for (int kx = 0; kx < 3; kx++) {
                int sx = col - kx;
                if ((sx & 1) || sx < 0) continue;
                int ix = sx >> 1;
                if (ix >= n_in) continue;
                acc += tw[ky * 3 + kx] * in_s[lr][ix];
            }
        }
        size_t idx = (size_t)b * n_out * n_out + (size_t)y * n_out + col;
        us_out[idx] += acc;
    }
}

extern "C" void kernel_launch(void* const* d_in, const int* in_sizes, int n_in,
                              void* d_out, int out_size, void* d_ws, size_t ws_size,
                              hipStream_t stream) {
    const float* u   = (const float*)d_in[0];
    const float* f   = (const float*)d_in[1];
    const float* a   = (const float*)d_in[2];
    const float* c0w = (const float*)d_in[3];
    const float* c0b = (const float*)d_in[4];
    const float* c1w = (const float*)d_in[5];
    const float* c1b = (const float*)d_in[6];
    const float* r1w = (const float*)d_in[7];
    const float* r3w = (const float*)d_in[8];
    const float* tw  = (const float*)d_in[9];
    float* out = (float*)d_out;
    float* ws  = (float*)d_ws;
    const size_t B = BATCH;

    // d_out layout: us0, f, a, diva0..diva4
    size_t off_us0 = 0;
    size_t off_f   = B * 16129;
    size_t off_a   = off_f + B * 16129;
    size_t off_d0  = off_a + B * 16384;
    size_t off_d1  = off_d0 + B * 16129;
    size_t off_d2  = off_d1 + B * 3969;
    size_t off_d3  = off_d2 + B * 961;
    size_t off_d4  = off_d3 + B * 225;

    // ws layout: r0, a1, r1, us1, us2
    size_t w_r0  = 0;
    size_t w_a1  = w_r0 + B * 16129;
    size_t w_r1  = w_a1 + B * 4096;
    size_t w_us1 = w_r1 + B * 3969;
    size_t w_us2 = w_us1 + B * 3969;

    dim3 blk(256);
    k_level0<<<dim3(8, B), blk, 0, stream>>>(
        u, f, a, c0w, c0b, c1w, c1b,
        out + off_us0, out + off_d0, ws + w_r0, out + off_f, out + off_a);

    k_restrict1<<<dim3(8, B), blk, 0, stream>>>(
        a, ws + w_r0, ws + w_a1, ws + w_r1, ws + w_us1, out + off_d1,
        r1w, r3w, c1w + 4, c1b + 1, c0w + 9, c0b + 1);

    k_coarse<<<dim3(1024), blk, 0, stream>>>(
        ws + w_a1, ws + w_r1, r1w, r3w, c1w, c1b, c0w, c0b, tw,
        out + off_d2, out + off_d3, out + off_d4, ws + w_us2);

    k_prolong<<<dim3(8, B), blk, 0, stream>>>(
        ws + w_us1, ws + w_us2, tw + 9, 63, 31);

    k_prolong<<<dim3(16, B), blk, 0, stream>>>(
        out + off_us0, ws + w_us1, tw + 0, 127, 63);
}

// Round 3
// 602.125 us; speedup vs baseline: 1.3717x; 1.0651x over previous
//
#include <hip/hip_runtime.h>
#include <cmath>

#define BATCH 1024

// ---------------- Fused Level 0 + Level 1 (r0 never hits HBM) ----------------
__global__ __launch_bounds__(256) void k_L01(
    const float* __restrict__ u, const float* __restrict__ f, const float* __restrict__ a,
    const float* __restrict__ c0w, const float* __restrict__ c0b,
    const float* __restrict__ c1w, const float* __restrict__ c1b,
    const float* __restrict__ r1w, const float* __restrict__ r3w,
    float* __restrict__ out_us0, float* __restrict__ out_diva0,
    float* __restrict__ out_f, float* __restrict__ out_a,
    float* __restrict__ out_diva1,
    float* __restrict__ ws_a1, float* __restrict__ ws_r1, float* __restrict__ ws_us1)
{
    const int b = blockIdx.y;
    const int bx = blockIdx.x;      // 0..7
    const int Y0 = bx * 16;         // level-0 row base
    const int y0 = bx * 8;          // level-1 row base
    const int tid = threadIdx.x;

    __shared__ float asrc[22][128];  // a rows Y0-2 .. Y0+19 (clamped)
    __shared__ float td0[18][128];   // tanh(diva0) rows Y0-1 .. Y0+16 (valid rows only)
    __shared__ float r0s[17][128];   // r0 rows Y0 .. Y0+16 (valid rows only)
    __shared__ float a1s[11][66];    // a1 rows y0-1..y0+9 (clamped), cols -1..64 (clamped)
    __shared__ float td1[10][64];    // tanh(diva1) rows y0-1..y0+8 (valid), cols 0..62

    const float* ab = a + (size_t)b * 16384;
    for (int i = tid; i < 22 * 128; i += 256) {
        int r = i >> 7, c = i & 127;
        int g = Y0 - 2 + r; g = g < 0 ? 0 : (g > 127 ? 127 : g);
        asrc[r][c] = ab[g * 128 + c];
    }
    __syncthreads();

    const float w00 = c1w[0], w01 = c1w[1], w10 = c1w[2], w11 = c1w[3], b1 = c1b[0];
    // td0: rows Y0-1 .. Y0+16  (asrc row for global row g is g-(Y0-2))
    for (int i = tid; i < 18 * 127; i += 256) {
        int r = i / 127, c = i % 127;
        int g = Y0 - 1 + r;
        if (g >= 0 && g <= 126) {
            float d = asrc[r + 1][c] * w00 + asrc[r + 1][c + 1] * w01
                    + asrc[r + 2][c] * w10 + asrc[r + 2][c + 1] * w11 + b1;
            td0[r][c] = tanhf(d);
        }
    }
    __syncthreads();

    // a passthrough: rows Y0..Y0+15 (always valid, a is 128 rows)
    {
        float* oa = out_a + (size_t)b * 16384 + (size_t)Y0 * 128;
        for (int i = tid; i < 16 * 128; i += 256)
            oa[i] = asrc[(i >> 7) + 2][i & 127];
    }

    // r0 rows Y0..Y0+16 into LDS; owned rows (first 16, g<=126) also emit
    // diva0, us0, f-passthrough
    const float c0b0 = c0b[0];
    for (int i = tid; i < 17 * 127; i += 256) {
        int rr = i / 127, c = i % 127;
        int g = Y0 + rr;
        if (g > 126) continue;
        float diva = asrc[rr + 2][c] * w00 + asrc[rr + 2][c + 1] * w01
                   + asrc[rr + 3][c] * w10 + asrc[rr + 3][c + 1] * w11 + b1;
        size_t idx = (size_t)b * 16129 + (size_t)g * 127 + c;
        float uv = u[idx], fv = f[idx];
        float rv = fv - diva * uv;
        r0s[rr][c] = rv;
        if (rr < 16) {
            float s = c0b0;
            #pragma unroll
            for (int ky = 0; ky < 3; ky++) {
                int sy = g - 1 + ky; sy = sy < 0 ? 0 : (sy > 126 ? 126 : sy);
                int lr = sy - (Y0 - 1);
                #pragma unroll
                for (int kx = 0; kx < 3; kx++) {
                    int sx = c - 1 + kx; sx = sx < 0 ? 0 : (sx > 126 ? 126 : sx);
                    s += c0w[ky * 3 + kx] * td0[lr][sx];
                }
            }
            out_diva0[idx] = diva;
            out_us0[idx] = uv + s * rv;
            out_f[idx] = fv;
        }
    }

    // level-1 restricted a: rows y0-1..y0+9 (clamped), cols -1..64 (clamped)
    const float q00 = r1w[0], q01 = r1w[1], q10 = r1w[2], q11 = r1w[3];
    for (int i = tid; i < 11 * 66; i += 256) {
        int rA = i / 66, cA = i % 66;
        int ay = y0 - 1 + rA; ay = ay < 0 ? 0 : (ay > 63 ? 63 : ay);
        int ax = cA - 1; ax = ax < 0 ? 0 : (ax > 63 ? 63 : ax);
        int la = 2 * ay - Y0 + 2;
        a1s[rA][cA] = asrc[la][2 * ax] * q00 + asrc[la][2 * ax + 1] * q01
                    + asrc[la + 1][2 * ax] * q10 + asrc[la + 1][2 * ax + 1] * q11;
    }
    __syncthreads();

    // a1 out: rows y0..y0+7 x 64 cols (contiguous 2KB)
    {
        float* a1o = ws_a1 + (size_t)b * 4096 + (size_t)y0 * 64;
        for (int i = tid; i < 8 * 64; i += 256)
            a1o[i] = a1s[(i >> 6) + 1][(i & 63) + 1];
    }

    const float v00 = c1w[4], v01 = c1w[5], v10 = c1w[6], v11 = c1w[7], b2 = c1b[1];
    // td1: rows y0-1..y0+8 (valid 0..62), cols 0..62
    for (int i = tid; i < 10 * 63; i += 256) {
        int rt = i / 63, c = i % 63;
        int dy = y0 - 1 + rt;
        if (dy >= 0 && dy <= 62) {
            float d = a1s[rt][c + 1] * v00 + a1s[rt][c + 2] * v01
                    + a1s[rt + 1][c + 1] * v10 + a1s[rt + 1][c + 2] * v11 + b2;
            td1[rt][c] = tanhf(d);
        }
    }
    __syncthreads();

    // level-1 outputs: rows y0..y0+7 (y<=62), cols 0..62
    const float c0b1 = c0b[1];
    const float* c0w1 = c0w + 9;
    const float* r3 = r3w;
    for (int i = tid; i < 8 * 63; i += 256) {
        int row = i / 63, col = i % 63;
        int y = y0 + row;
        if (y > 62) continue;
        float diva = a1s[row + 1][col + 1] * v00 + a1s[row + 1][col + 2] * v01
                   + a1s[row + 2][col + 1] * v10 + a1s[row + 2][col + 2] * v11 + b2;
        float rv = 0.f;
        #pragma unroll
        for (int p = 0; p < 3; p++)
            #pragma unroll
            for (int q = 0; q < 3; q++)
                rv += r3[p * 3 + q] * r0s[2 * row + p][2 * col + q];
        float s = c0b1;
        #pragma unroll
        for (int ky = 0; ky < 3; ky++) {
            int sy = y - 1 + ky; sy = sy < 0 ? 0 : (sy > 62 ? 62 : sy);
            int lr = sy - (y0 - 1);
            #pragma unroll
            for (int kx = 0; kx < 3; kx++) {
                int sx = col - 1 + kx; sx = sx < 0 ? 0 : (sx > 62 ? 62 : sx);
                s += c0w1[ky * 3 + kx] * td1[lr][sx];
            }
        }
        size_t idx = (size_t)b * 3969 + (size_t)y * 63 + col;
        out_diva1[idx] = diva;
        ws_r1[idx] = rv;
        ws_us1[idx] = s * rv;
    }
}

// ---------------- Fused levels 2..4 + prolong 4->3->2 (one block per image) ----------------
template<int N, int NA, int PA, int PD>
__device__ __forceinline__ void level_step(
    const float* ap, const float* rp, float* ac, float* rc, float* us, float* td,
    const float* __restrict__ r1w, const float* __restrict__ r3w,
    const float* __restrict__ c1w, float c1b_,
    const float* __restrict__ c0w, float c0b_,
    float* __restrict__ diva_out, int tid)
{
    const float q00 = r1w[0], q01 = r1w[1], q10 = r1w[2], q11 = r1w[3];
    for (int idx = tid; idx < NA * NA; idx += 256) {
        int y = idx / NA, x = idx % NA;
        const float* p = ap + 2 * y * PA + 2 * x;
        ac[idx] = p[0] * q00 + p[1] * q01 + p[PA] * q10 + p[PA + 1] * q11;
    }
    __syncthreads();
    const float w00 = c1w[0], w01 = c1w[1], w10 = c1w[2], w11 = c1w[3];
    for (int idx = tid; idx < N * N; idx += 256) {
        int y = idx / N, x = idx % N;
        float d = ac[y * NA + x] * w00 + ac[y * NA + x + 1] * w01
                + ac[(y + 1) * NA + x] * w10 + ac[(y + 1) * NA + x + 1] * w11 + c1b_;
        td[idx] = tanhf(d);
        diva_out[idx] = d;
    }
    __syncthreads();
    for (int idx = tid; idx < N * N; idx += 256) {
        int y = idx / N, x = idx % N;
        float rv = 0.f;
        #pragma unroll
        for (int p = 0; p < 3; p++)
            #pragma unroll
            for (int q = 0; q < 3; q++)
                rv += r3w[p * 3 + q] * rp[(2 * y + p) * PD + 2 * x + q];
        float s = c0b_;
        #pragma unroll
        for (int ky = 0; ky < 3; ky++) {
            int sy = y - 1 + ky; sy = sy < 0 ? 0 : (sy > N - 1 ? N - 1 : sy);
            #pragma unroll
            for (int kx = 0; kx < 3; kx++) {
                int sx = x - 1 + kx; sx = sx < 0 ? 0 : (sx > N - 1 ? N - 1 : sx);
                s += c0w[ky * 3 + kx] * td[sy * N + sx];
            }
        }
        rc[idx] = rv;
        us[idx] = s * rv;
    }
    __syncthreads();
}

template<int NO, int NI>
__device__ __forceinline__ void prolong_step(
    float* uo, const float* ui, const float* __restrict__ tw9, int tid)
{
    for (int idx = tid; idx < NO * NO; idx += 256) {
        int y = idx / NO, x = idx % NO;
        float acc = 0.f;
        #pragma unroll
        for (int ky = 0; ky < 3; ky++) {
            int sy = y - ky;
            if (sy & 1) continue;
            int iy = sy >> 1;
            if (iy < 0 || iy >= NI) continue;
            #pragma unroll
            for (int kx = 0; kx < 3; kx++) {
                int sx = x - kx;
                if (sx & 1) continue;
                int ix = sx >> 1;
                if (ix < 0 || ix >= NI) continue;
                acc += tw9[ky * 3 + kx] * ui[iy * NI + ix];
            }
        }
        uo[idx] += acc;
    }
    __syncthreads();
}

__global__ __launch_bounds__(256) void k_coarse(
    const float* __restrict__ a1, const float* __restrict__ r1,
    const float* __restrict__ r1w, const float* __restrict__ r3w,
    const float* __restrict__ c1w, const float* __restrict__ c1b,
    const float* __restrict__ c0w, const float* __restrict__ c0b,
    const float* __restrict__ tw,
    float* __restrict__ diva2, float* __restrict__ diva3, float* __restrict__ diva4,
    float* __restrict__ us2_out)
{
    const int b = blockIdx.x;
    const int tid = threadIdx.x;
    __shared__ float aA[64 * 64];
    __shared__ float rA[63 * 63];
    __shared__ float aB[32 * 32];
    __shared__ float rB[31 * 31];
    __shared__ float aC[16 * 16];
    __shared__ float rC[15 * 15];
    __shared__ float aD[8 * 8];
    __shared__ float rD[7 * 7];
    __shared__ float us2s[31 * 31];
    __shared__ float us3s[15 * 15];
    __shared__ float us4s[7 * 7];
    __shared__ float td[31 * 31];

    const float* a1b = a1 + (size_t)b * 4096;
    const float* r1b = r1 + (size_t)b * 3969;
    for (int i = tid; i < 4096; i += 256) aA[i] = a1b[i];
    for (int i = tid; i < 3969; i += 256) rA[i] = r1b[i];
    __syncthreads();

    level_step<31, 32, 64, 63>(aA, rA, aB, rB, us2s, td,
        r1w + 4, r3w + 9, c1w + 8, c1b[2], c0w + 18, c0b[2],
        diva2 + (size_t)b * 961, tid);
    level_step<15, 16, 32, 31>(aB, rB, aC, rC, us3s, td,
        r1w + 8, r3w + 18, c1w + 12, c1b[3], c0w + 27, c0b[3],
        diva3 + (size_t)b * 225, tid);
    level_step<7, 8, 16, 15>(aC, rC, aD, rD, us4s, td,
        r1w + 12, r3w + 27, c1w + 16, c1b[4], c0w + 36, c0b[4],
        diva4 + (size_t)b * 49, tid);

    prolong_step<15, 7>(us3s, us4s, tw + 27, tid);
    prolong_step<31, 15>(us2s, us3s, tw + 18, tid);

    for (int i = tid; i < 961; i += 256)
        us2_out[(size_t)b * 961 + i] = us2s[i];
}

// ---------------- Fused prolong: us1'=us1+convT(us2') in LDS, then us0 += convT(us1') ----------------
__global__ __launch_bounds__(256) void k_prolong2(
    float* __restrict__ us0, const float* __restrict__ us1, const float* __restrict__ us2,
    const float* __restrict__ tw)   // tw+0: level0<-1 weights, tw+9: level1<-2 weights
{
    const int b = blockIdx.y;
    const int bx = blockIdx.x;       // 0..7
    const int Y0 = bx * 16;          // us0 row base
    const int y0 = bx * 8;           // us1 row base
    const int tid = threadIdx.x;
    __shared__ float us2s[6][32];    // us2' rows 4bx-2 .. 4bx+3 (valid only)
    __shared__ float us1p[9][64];    // us1' rows y0-1 .. y0+7 (valid only)

    const float* i2 = us2 + (size_t)b * 961;
    for (int i = tid; i < 6 * 31; i += 256) {
        int r = i / 31, c = i % 31;
        int jy = 4 * bx - 2 + r;
        if (jy >= 0 && jy <= 30) us2s[r][c] = i2[jy * 31 + c];
    }
    __syncthreads();

    const float* t1 = tw + 9;
    const float* i1 = us1 + (size_t)b * 3969;
    for (int i = tid; i < 9 * 63; i += 256) {
        int r = i / 63, c = i % 63;
        int iy = y0 - 1 + r;
        if (iy < 0 || iy > 62) continue;
        float acc = i1[iy * 63 + c];
        #pragma unroll
        for (int ky = 0; ky < 3; ky++) {
            int sy = iy - ky;
            if ((sy & 1) || sy < 0) continue;
            int jy = sy >> 1;
            if (jy > 30) continue;
            int lr = jy - (4 * bx - 2);
            #pragma unroll
            for (int kx = 0; kx < 3; kx++) {
                int sx = c - kx;
                if ((sx & 1) || sx < 0) continue;
                int jx = sx >> 1;
                if (jx > 30) continue;
                acc += t1[ky * 3 + kx] * us2s[lr][jx];
            }
        }
        us1p[r][c] = acc;
    }
    __syncthreads();

    const float* t0 = tw;
    float* o0 = us0 + (size_t)b * 16129;
    for (int i = tid; i < 16 * 127; i += 256) {
        int row = i / 127, col = i % 127;
        int y = Y0 + row;
        if (y > 126) continue;
        float acc = 0.f;
        #pragma unroll
        for (int ky = 0; ky < 3; ky++) {
            int sy = y - ky;
            if ((sy & 1) || sy < 0) continue;
            int iy = sy >> 1;
            if (iy > 62) continue;
            int lr = iy - (y0 - 1);
            #pragma unroll
            for (int kx = 0; kx < 3; kx++) {
                int sx = col - kx;
                if ((sx & 1) || sx < 0) continue;
                int ix = sx >> 1;
                if (ix > 62) continue;
                acc += t0[ky * 3 + kx] * us1p[lr][ix];
            }
        }
        o0[(size_t)y * 127 + col] += acc;
    }
}

extern "C" void kernel_launch(void* const* d_in, const int* in_sizes, int n_in,
                              void* d_out, int out_size, void* d_ws, size_t ws_size,
                              hipStream_t stream) {
    const float* u   = (const float*)d_in[0];
    const float* f   = (const float*)d_in[1];
    const float* a   = (const float*)d_in[2];
    const float* c0w = (const float*)d_in[3];
    const float* c0b = (const float*)d_in[4];
    const float* c1w = (const float*)d_in[5];
    const float* c1b = (const float*)d_in[6];
    const float* r1w = (const float*)d_in[7];
    const float* r3w = (const float*)d_in[8];
    const float* tw  = (const float*)d_in[9];
    float* out = (float*)d_out;
    float* ws  = (float*)d_ws;
    const size_t B = BATCH;

    // d_out layout: us0, f, a, diva0..diva4
    size_t off_us0 = 0;
    size_t off_f   = B * 16129;
    size_t off_a   = off_f + B * 16129;
    size_t off_d0  = off_a + B * 16384;
    size_t off_d1  = off_d0 + B * 16129;
    size_t off_d2  = off_d1 + B * 3969;
    size_t off_d3  = off_d2 + B * 961;
    size_t off_d4  = off_d3 + B * 225;

    // ws layout: a1, r1, us1, us2
    size_t w_a1  = 0;
    size_t w_r1  = w_a1 + B * 4096;
    size_t w_us1 = w_r1 + B * 3969;
    size_t w_us2 = w_us1 + B * 3969;

    dim3 blk(256);
    k_L01<<<dim3(8, B), blk, 0, stream>>>(
        u, f, a, c0w, c0b, c1w, c1b, r1w, r3w,
        out + off_us0, out + off_d0, out + off_f, out + off_a,
        out + off_d1, ws + w_a1, ws + w_r1, ws + w_us1);

    k_coarse<<<dim3(1024), blk, 0, stream>>>(
        ws + w_a1, ws + w_r1, r1w, r3w, c1w, c1b, c0w, c0b, tw,
        out + off_d2, out + off_d3, out + off_d4, ws + w_us2);

    k_prolong2<<<dim3(8, B), blk, 0, stream>>>(
        out + off_us0, ws + w_us1, ws + w_us2, tw);
}

// Round 4
// 510.982 us; speedup vs baseline: 1.6164x; 1.1784x over previous
//
#include <hip/hip_runtime.h>
#include <cmath>

#define BATCH 1024

// ---------------- Fused Level 0 + Level 1, 8-row stripes, high occupancy ----------------
__global__ __launch_bounds__(256, 8) void k_L01(
    const float* __restrict__ u, const float* __restrict__ f, const float* __restrict__ a,
    const float* __restrict__ c0w, const float* __restrict__ c0b,
    const float* __restrict__ c1w, const float* __restrict__ c1b,
    const float* __restrict__ r1w, const float* __restrict__ r3w,
    float* __restrict__ out_us0, float* __restrict__ out_diva0,
    float* __restrict__ out_f, float* __restrict__ out_a,
    float* __restrict__ out_diva1,
    float* __restrict__ ws_a1, float* __restrict__ ws_r1, float* __restrict__ ws_us1)
{
    const int b = blockIdx.y;
    const int bx = blockIdx.x;      // 0..15
    const int Y0 = bx * 8;          // level-0 row base
    const int y0 = bx * 4;          // level-1 row base
    const int tid = threadIdx.x;

    __shared__ float asrc[14][128];  // a rows Y0-2 .. Y0+11 (clamped)
    __shared__ float td0[10][128];   // tanh(diva0) rows Y0-1 .. Y0+8 (valid only)
    __shared__ float r0s[9][128];    // r0 rows Y0 .. Y0+8 (valid only)
    __shared__ float a1s[7][68];     // a1 rows y0-1..y0+5 (clamped), cols -1..64 (clamped)
    __shared__ float td1[6][64];     // tanh(diva1) rows y0-1..y0+4 (valid), cols 0..62

    // ---- A: stage a rows (float4, fully coalesced) ----
    {
        const float4* ab4 = reinterpret_cast<const float4*>(a + (size_t)b * 16384);
        float4* s4 = reinterpret_cast<float4*>(&asrc[0][0]);
        const int c4 = tid & 31, r4 = tid >> 5;
        #pragma unroll
        for (int r = r4; r < 14; r += 8) {
            int g = Y0 - 2 + r; g = g < 0 ? 0 : (g > 127 ? 127 : g);
            s4[r * 32 + c4] = ab4[g * 32 + c4];
        }
    }
    __syncthreads();

    const float w00 = c1w[0], w01 = c1w[1], w10 = c1w[2], w11 = c1w[3], b1 = c1b[0];
    const int tx = tid & 127, ty = tid >> 7;

    // ---- B: td0 rows Y0-1..Y0+8 ----
    #pragma unroll
    for (int r = ty; r < 10; r += 2) {
        int g = Y0 - 1 + r;
        if (g >= 0 && g <= 126 && tx < 127) {
            float d = asrc[r + 1][tx] * w00 + asrc[r + 1][tx + 1] * w01
                    + asrc[r + 2][tx] * w10 + asrc[r + 2][tx + 1] * w11 + b1;
            td0[r][tx] = tanhf(d);
        }
    }
    // ---- P: a passthrough rows Y0..Y0+7 (float4) ----
    {
        float4* oa4 = reinterpret_cast<float4*>(out_a + (size_t)b * 16384);
        const float4* s4 = reinterpret_cast<const float4*>(&asrc[0][0]);
        const int c4 = tid & 31, r4 = tid >> 5;
        oa4[(Y0 + r4) * 32 + c4] = s4[(r4 + 2) * 32 + c4];
    }
    // ---- D: a1 restriction (reads asrc only) ----
    const float q00 = r1w[0], q01 = r1w[1], q10 = r1w[2], q11 = r1w[3];
    {
        const int tx2 = tid & 63, ty2 = tid >> 6;
        #pragma unroll
        for (int r = ty2; r < 7; r += 4)
            for (int c = tx2; c < 66; c += 64) {
                int ay = y0 - 1 + r; ay = ay < 0 ? 0 : (ay > 63 ? 63 : ay);
                int ax = c - 1; ax = ax < 0 ? 0 : (ax > 63 ? 63 : ax);
                int la = 2 * ay - (Y0 - 2);
                a1s[r][c] = asrc[la][2 * ax] * q00 + asrc[la][2 * ax + 1] * q01
                          + asrc[la + 1][2 * ax] * q10 + asrc[la + 1][2 * ax + 1] * q11;
            }
    }
    __syncthreads();

    // ---- C: r0s + level-0 outputs ----
    const float c0b0 = c0b[0];
    #pragma unroll
    for (int rr = ty; rr < 9; rr += 2) {
        int g = Y0 + rr;
        if (g > 126 || tx >= 127) continue;
        float diva = asrc[rr + 2][tx] * w00 + asrc[rr + 2][tx + 1] * w01
                   + asrc[rr + 3][tx] * w10 + asrc[rr + 3][tx + 1] * w11 + b1;
        size_t idx = (size_t)b * 16129 + (size_t)g * 127 + tx;
        float uv = u[idx], fv = f[idx];
        float rv = fv - diva * uv;
        r0s[rr][tx] = rv;
        if (rr < 8) {
            float s = c0b0;
            #pragma unroll
            for (int ky = 0; ky < 3; ky++) {
                int sy = g - 1 + ky; sy = sy < 0 ? 0 : (sy > 126 ? 126 : sy);
                int lr = sy - (Y0 - 1);
                #pragma unroll
                for (int kx = 0; kx < 3; kx++) {
                    int sx = tx - 1 + kx; sx = sx < 0 ? 0 : (sx > 126 ? 126 : sx);
                    s += c0w[ky * 3 + kx] * td0[lr][sx];
                }
            }
            out_diva0[idx] = diva;
            out_us0[idx] = uv + s * rv;
            out_f[idx] = fv;
        }
    }

    // ---- E: a1 out + td1 ----
    const float v00 = c1w[4], v01 = c1w[5], v10 = c1w[6], v11 = c1w[7], b2 = c1b[1];
    {
        const int tx2 = tid & 63, ty2 = tid >> 6;
        ws_a1[(size_t)b * 4096 + (size_t)(y0 + ty2) * 64 + tx2] = a1s[ty2 + 1][tx2 + 1];
        #pragma unroll
        for (int r = ty2; r < 6; r += 4) {
            int dy = y0 - 1 + r;
            if (dy >= 0 && dy <= 62 && tx2 < 63) {
                float d = a1s[r][tx2 + 1] * v00 + a1s[r][tx2 + 2] * v01
                        + a1s[r + 1][tx2 + 1] * v10 + a1s[r + 1][tx2 + 2] * v11 + b2;
                td1[r][tx2] = tanhf(d);
            }
        }
    }
    __syncthreads();

    // ---- F: level-1 outputs rows y0..y0+3 ----
    {
        const int tx2 = tid & 63, ty2 = tid >> 6;
        const int y = y0 + ty2;
        if (y <= 62 && tx2 < 63) {
            float diva = a1s[ty2 + 1][tx2 + 1] * v00 + a1s[ty2 + 1][tx2 + 2] * v01
                       + a1s[ty2 + 2][tx2 + 1] * v10 + a1s[ty2 + 2][tx2 + 2] * v11 + b2;
            float rv = 0.f;
            #pragma unroll
            for (int p = 0; p < 3; p++)
                #pragma unroll
                for (int q = 0; q < 3; q++)
                    rv += r3w[p * 3 + q] * r0s[2 * ty2 + p][2 * tx2 + q];
            float s = c0b[1];
            #pragma unroll
            for (int ky = 0; ky < 3; ky++) {
                int sy = y - 1 + ky; sy = sy < 0 ? 0 : (sy > 62 ? 62 : sy);
                int lr = sy - (y0 - 1);
                #pragma unroll
                for (int kx = 0; kx < 3; kx++) {
                    int sx = tx2 - 1 + kx; sx = sx < 0 ? 0 : (sx > 62 ? 62 : sx);
                    s += c0w[9 + ky * 3 + kx] * td1[lr][sx];
                }
            }
            size_t idx = (size_t)b * 3969 + (size_t)y * 63 + tx2;
            out_diva1[idx] = diva;
            ws_r1[idx] = rv;
            ws_us1[idx] = s * rv;
        }
    }
}

// ---------------- Fused levels 2..4 + prolong 4->3->2 (one block per image) ----------------
template<int N, int NA, int PA, int PD>
__device__ __forceinline__ void level_step(
    const float* ap, const float* rp, float* ac, float* rc, float* us, float* td,
    const float* __restrict__ r1w, const float* __restrict__ r3w,
    const float* __restrict__ c1w, float c1b_,
    const float* __restrict__ c0w, float c0b_,
    float* __restrict__ diva_out, int tid)
{
    const float q00 = r1w[0], q01 = r1w[1], q10 = r1w[2], q11 = r1w[3];
    for (int idx = tid; idx < NA * NA; idx += 256) {
        int y = idx / NA, x = idx % NA;
        const float* p = ap + 2 * y * PA + 2 * x;
        ac[idx] = p[0] * q00 + p[1] * q01 + p[PA] * q10 + p[PA + 1] * q11;
    }
    __syncthreads();
    const float w00 = c1w[0], w01 = c1w[1], w10 = c1w[2], w11 = c1w[3];
    for (int idx = tid; idx < N * N; idx += 256) {
        int y = idx / N, x = idx % N;
        float d = ac[y * NA + x] * w00 + ac[y * NA + x + 1] * w01
                + ac[(y + 1) * NA + x] * w10 + ac[(y + 1) * NA + x + 1] * w11 + c1b_;
        td[idx] = tanhf(d);
        diva_out[idx] = d;
    }
    __syncthreads();
    for (int idx = tid; idx < N * N; idx += 256) {
        int y = idx / N, x = idx % N;
        float rv = 0.f;
        #pragma unroll
        for (int p = 0; p < 3; p++)
            #pragma unroll
            for (int q = 0; q < 3; q++)
                rv += r3w[p * 3 + q] * rp[(2 * y + p) * PD + 2 * x + q];
        float s = c0b_;
        #pragma unroll
        for (int ky = 0; ky < 3; ky++) {
            int sy = y - 1 + ky; sy = sy < 0 ? 0 : (sy > N - 1 ? N - 1 : sy);
            #pragma unroll
            for (int kx = 0; kx < 3; kx++) {
                int sx = x - 1 + kx; sx = sx < 0 ? 0 : (sx > N - 1 ? N - 1 : sx);
                s += c0w[ky * 3 + kx] * td[sy * N + sx];
            }
        }
        rc[idx] = rv;
        us[idx] = s * rv;
    }
    __syncthreads();
}

template<int NO, int NI>
__device__ __forceinline__ void prolong_step(
    float* uo, const float* ui, const float* __restrict__ tw9, int tid)
{
    for (int idx = tid; idx < NO * NO; idx += 256) {
        int y = idx / NO, x = idx % NO;
        float acc = 0.f;
        #pragma unroll
        for (int ky = 0; ky < 3; ky++) {
            int sy = y - ky;
            if (sy & 1) continue;
            int iy = sy >> 1;
            if (iy < 0 || iy >= NI) continue;
            #pragma unroll
            for (int kx = 0; kx < 3; kx++) {
                int sx = x - kx;
                if (sx & 1) continue;
                int ix = sx >> 1;
                if (ix < 0 || ix >= NI) continue;
                acc += tw9[ky * 3 + kx] * ui[iy * NI + ix];
            }
        }
        uo[idx] += acc;
    }
    __syncthreads();
}

__global__ __launch_bounds__(256) void k_coarse(
    const float* __restrict__ a1, const float* __restrict__ r1,
    const float* __restrict__ r1w, const float* __restrict__ r3w,
    const float* __restrict__ c1w, const float* __restrict__ c1b,
    const float* __restrict__ c0w, const float* __restrict__ c0b,
    const float* __restrict__ tw,
    float* __restrict__ diva2, float* __restrict__ diva3, float* __restrict__ diva4,
    float* __restrict__ us2_out)
{
    const int b = blockIdx.x;
    const int tid = threadIdx.x;
    __shared__ float aB[32 * 32];
    __shared__ float rB[31 * 31];
    __shared__ float aC[16 * 16];
    __shared__ float rC[15 * 15];
    __shared__ float aD[8 * 8];
    __shared__ float rD[7 * 7];
    __shared__ float us2s[31 * 31];
    __shared__ float us3s[15 * 15];
    __shared__ float us4s[7 * 7];
    __shared__ float td[31 * 31];

    // level 2 reads a1/r1 straight from global (restriction has no reuse;
    // r1's 15.5 KB block working set is L1-resident)
    level_step<31, 32, 64, 63>(a1 + (size_t)b * 4096, r1 + (size_t)b * 3969,
        aB, rB, us2s, td,
        r1w + 4, r3w + 9, c1w + 8, c1b[2], c0w + 18, c0b[2],
        diva2 + (size_t)b * 961, tid);
    level_step<15, 16, 32, 31>(aB, rB, aC, rC, us3s, td,
        r1w + 8, r3w + 18, c1w + 12, c1b[3], c0w + 27, c0b[3],
        diva3 + (size_t)b * 225, tid);
    level_step<7, 8, 16, 15>(aC, rC, aD, rD, us4s, td,
        r1w + 12, r3w + 27, c1w + 16, c1b[4], c0w + 36, c0b[4],
        diva4 + (size_t)b * 49, tid);

    prolong_step<15, 7>(us3s, us4s, tw + 27, tid);
    prolong_step<31, 15>(us2s, us3s, tw + 18, tid);

    for (int i = tid; i < 961; i += 256)
        us2_out[(size_t)b * 961 + i] = us2s[i];
}

// ---------------- Fused prolong: us1'=us1+convT(us2') in LDS, then us0 += convT(us1') ----------------
__global__ __launch_bounds__(256) void k_prolong2(
    float* __restrict__ us0, const float* __restrict__ us1, const float* __restrict__ us2,
    const float* __restrict__ tw)   // tw+0: level0<-1 weights, tw+9: level1<-2 weights
{
    const int b = blockIdx.y;
    const int bx = blockIdx.x;       // 0..7
    const int Y0 = bx * 16;          // us0 row base
    const int y0 = bx * 8;           // us1 row base
    const int tid = threadIdx.x;
    __shared__ float us2s[6][32];    // us2' rows 4bx-2 .. 4bx+3 (valid only)
    __shared__ float us1p[9][64];    // us1' rows y0-1 .. y0+7 (valid only)

    {
        const float* i2 = us2 + (size_t)b * 961;
        const int tx3 = tid & 31, ty3 = tid >> 5;
        if (ty3 < 6 && tx3 < 31) {
            int jy = 4 * bx - 2 + ty3;
            if (jy >= 0 && jy <= 30) us2s[ty3][tx3] = i2[jy * 31 + tx3];
        }
    }
    __syncthreads();

    const float* t1 = tw + 9;
    {
        const float* i1 = us1 + (size_t)b * 3969;
        const int tx2 = tid & 63, ty2 = tid >> 6;
        #pragma unroll
        for (int r = ty2; r < 9; r += 4) {
            int iy = y0 - 1 + r;
            if (iy < 0 || iy > 62 || tx2 >= 63) continue;
            float acc = i1[iy * 63 + tx2];
            #pragma unroll
            for (int ky = 0; ky < 3; ky++) {
                int sy = iy - ky;
                if ((sy & 1) || sy < 0) continue;
                int jy = sy >> 1;
                if (jy > 30) continue;
                int lr = jy - (4 * bx - 2);
                #pragma unroll
                for (int kx = 0; kx < 3; kx++) {
                    int sx = tx2 - kx;
                    if ((sx & 1) || sx < 0) continue;
                    int jx = sx >> 1;
                    if (jx > 30) continue;
                    acc += t1[ky * 3 + kx] * us2s[lr][jx];
                }
            }
            us1p[r][tx2] = acc;
        }
    }
    __syncthreads();

    const float* t0 = tw;
    {
        float* o0 = us0 + (size_t)b * 16129;
        const int tx = tid & 127, ty = tid >> 7;
        #pragma unroll
        for (int row = ty; row < 16; row += 2) {
            int y = Y0 + row;
            if (y > 126 || tx >= 127) continue;
            float acc = 0.f;
            #pragma unroll
            for (int ky = 0; ky < 3; ky++) {
                int sy = y - ky;
                if ((sy & 1) || sy < 0) continue;
                int iy = sy >> 1;
                if (iy > 62) continue;
                int lr = iy - (y0 - 1);
                #pragma unroll
                for (int kx = 0; kx < 3; kx++) {
                    int sx = tx - kx;
                    if ((sx & 1) || sx < 0) continue;
                    int ix = sx >> 1;
                    if (ix > 62) continue;
                    acc += t0[ky * 3 + kx] * us1p[lr][ix];
                }
            }
            o0[(size_t)y * 127 + tx] += acc;
        }
    }
}

extern "C" void kernel_launch(void* const* d_in, const int* in_sizes, int n_in,
                              void* d_out, int out_size, void* d_ws, size_t ws_size,
                              hipStream_t stream) {
    const float* u   = (const float*)d_in[0];
    const float* f   = (const float*)d_in[1];
    const float* a   = (const float*)d_in[2];
    const float* c0w = (const float*)d_in[3];
    const float* c0b = (const float*)d_in[4];
    const float* c1w = (const float*)d_in[5];
    const float* c1b = (const float*)d_in[6];
    const float* r1w = (const float*)d_in[7];
    const float* r3w = (const float*)d_in[8];
    const float* tw  = (const float*)d_in[9];
    float* out = (float*)d_out;
    float* ws  = (float*)d_ws;
    const size_t B = BATCH;

    // d_out layout: us0, f, a, diva0..diva4
    size_t off_us0 = 0;
    size_t off_f   = B * 16129;
    size_t off_a   = off_f + B * 16129;
    size_t off_d0  = off_a + B * 16384;
    size_t off_d1  = off_d0 + B * 16129;
    size_t off_d2  = off_d1 + B * 3969;
    size_t off_d3  = off_d2 + B * 961;
    size_t off_d4  = off_d3 + B * 225;

    // ws layout: a1, r1, us1, us2
    size_t w_a1  = 0;
    size_t w_r1  = w_a1 + B * 4096;
    size_t w_us1 = w_r1 + B * 3969;
    size_t w_us2 = w_us1 + B * 3969;

    dim3 blk(256);
    k_L01<<<dim3(16, B), blk, 0, stream>>>(
        u, f, a, c0w, c0b, c1w, c1b, r1w, r3w,
        out + off_us0, out + off_d0, out + off_f, out + off_a,
        out + off_d1, ws + w_a1, ws + w_r1, ws + w_us1);

    k_coarse<<<dim3(1024), blk, 0, stream>>>(
        ws + w_a1, ws + w_r1, r1w, r3w, c1w, c1b, c0w, c0b, tw,
        out + off_d2, out + off_d3, out + off_d4, ws + w_us2);

    k_prolong2<<<dim3(8, B), blk, 0, stream>>>(
        out + off_us0, ws + w_us1, ws + w_us2, tw);
}